// Round 2
// baseline (1112.527 us; speedup 1.0000x reference)
//
#include <hip/hip_runtime.h>

#define NB   32
#define C1   60
#define C2   128
#define HDIM 128

// ws layout (floats)
#define WS_LAP    0
#define WS_BIAS1  1024
#define WS_BIAS2  1152
#define WS_W1P    1280                  // 4*60*128  = 30720
#define WS_W2P    (1280 + 30720)        // 4*128*128 = 65536

#define FMA4(d, a, v)                      \
  d.x = fmaf((a), (v).x, d.x);             \
  d.y = fmaf((a), (v).y, d.y);             \
  d.z = fmaf((a), (v).z, d.z);             \
  d.w = fmaf((a), (v).w, d.w)

__global__ void prep_kernel(const float* __restrict__ adj,
                            const float* __restrict__ adj_bias,
                            const float* __restrict__ w1,
                            const float* __restrict__ b1,
                            const float* __restrict__ w2,
                            const float* __restrict__ b2,
                            float* __restrict__ ws) {
  const int tid = threadIdx.x;
  const int blk = blockIdx.x;
  if (blk == 0) {
    __shared__ float sa[1024];
    __shared__ float sdre[32];
    float bias = adj_bias[0];
    for (int i = tid; i < 1024; i += 256) sa[i] = fmaxf(adj[i] + bias, 0.0f);
    __syncthreads();
    if (tid < 32) {
      float s = 0.0f;
      for (int c = 0; c < 32; ++c) s += sa[tid * 32 + c];
      sdre[tid] = 1.0f / sqrtf(s + 1e-5f);
    }
    __syncthreads();
    for (int i = tid; i < 1024; i += 256) {
      int n = i >> 5, c = i & 31;
      ws[WS_LAP + i] = (n == c ? 1.0f : 0.0f) - sdre[n] * sa[i] * sdre[c];
    }
    // fold the T0(=ones) einsum term into the bias
    if (tid < 128) {
      float s = b1[tid];
      for (int c = 0; c < C1; ++c) s += w1[(c * 5) * HDIM + tid];
      ws[WS_BIAS1 + tid] = s;
    } else {
      int o = tid - 128;
      float s = b2[o];
      for (int c = 0; c < C2; ++c) s += w2[(c * 5) * HDIM + o];
      ws[WS_BIAS2 + o] = s;
    }
  } else {
    // pack W1p[k][c][o] = w1[c*5 + k + 1][o]  (k = 0..3 <-> cheb term 1..4)
    int g = (blk - 1) * 256 + tid;
    const int STR = 32 * 256;
    for (int i = g; i < 4 * C1 * HDIM; i += STR) {
      int o = i & 127, kc = i >> 7;
      int k = kc / C1, c = kc - k * C1;
      ws[WS_W1P + i] = w1[(c * 5 + k + 1) * HDIM + o];
    }
    for (int i = g; i < 4 * C2 * HDIM; i += STR) {
      int o = i & 127, kc = i >> 7;
      int k = kc >> 7, c = kc & 127;
      ws[WS_W2P + i] = w2[(c * 5 + k + 1) * HDIM + o];
    }
  }
}

// acc[n-tile 4][o-tile 4] += S[32xC] @ Wk[Cx128] sub-tile
template <int C>
__device__ __forceinline__ void einsum_acc(const float* __restrict__ S,
                                           const float* __restrict__ Wk,
                                           int n0, int o0, float acc[4][4]) {
#pragma unroll 4
  for (int c0 = 0; c0 < C; c0 += 4) {
    float sv[4][4];
#pragma unroll
    for (int i = 0; i < 4; ++i) {
      float4 t = *(const float4*)&S[(n0 + i) * C + c0];
      sv[i][0] = t.x; sv[i][1] = t.y; sv[i][2] = t.z; sv[i][3] = t.w;
    }
#pragma unroll
    for (int j = 0; j < 4; ++j) {
      float4 wv = *(const float4*)&Wk[(c0 + j) * HDIM + o0];
#pragma unroll
      for (int i = 0; i < 4; ++i) {
        acc[i][0] = fmaf(sv[i][j], wv.x, acc[i][0]);
        acc[i][1] = fmaf(sv[i][j], wv.y, acc[i][1]);
        acc[i][2] = fmaf(sv[i][j], wv.z, acc[i][2]);
        acc[i][3] = fmaf(sv[i][j], wv.w, acc[i][3]);
      }
    }
  }
}

// REC=false: dst = L @ src ;  REC=true: dst = 2*(L @ src) - dst   (C1 = 60 cols)
template <bool REC>
__device__ __forceinline__ void cheb60(float* __restrict__ dst,
                                       const float* __restrict__ src,
                                       const float* __restrict__ sL, int tid) {
  const int n = tid >> 3;
  const int c0 = (tid & 7) * 8;
  const bool full = (c0 + 8) <= C1;  // second float4 valid (cg < 7)
  float4 s0 = make_float4(0, 0, 0, 0);
  float4 s1 = make_float4(0, 0, 0, 0);
#pragma unroll 8
  for (int m = 0; m < 32; ++m) {
    float l = sL[n * 32 + m];
    float4 v0 = *(const float4*)&src[m * C1 + c0];
    FMA4(s0, l, v0);
    if (full) {
      float4 v1 = *(const float4*)&src[m * C1 + c0 + 4];
      FMA4(s1, l, v1);
    }
  }
  if (REC) {
    float4 o0v = *(const float4*)&dst[n * C1 + c0];
    s0.x = 2.0f * s0.x - o0v.x; s0.y = 2.0f * s0.y - o0v.y;
    s0.z = 2.0f * s0.z - o0v.z; s0.w = 2.0f * s0.w - o0v.w;
  }
  *(float4*)&dst[n * C1 + c0] = s0;
  if (full) {
    if (REC) {
      float4 o1v = *(const float4*)&dst[n * C1 + c0 + 4];
      s1.x = 2.0f * s1.x - o1v.x; s1.y = 2.0f * s1.y - o1v.y;
      s1.z = 2.0f * s1.z - o1v.z; s1.w = 2.0f * s1.w - o1v.w;
    }
    *(float4*)&dst[n * C1 + c0 + 4] = s1;
  }
}

template <bool REC>
__device__ __forceinline__ void cheb128(float* __restrict__ dst,
                                        const float* __restrict__ src,
                                        const float* __restrict__ sL, int tid) {
  const int n0c = (tid >> 4) * 2;   // 2 rows per thread
  const int c0 = (tid & 15) * 8;    // 8 cols per thread
  float4 s00 = make_float4(0, 0, 0, 0), s01 = make_float4(0, 0, 0, 0);
  float4 s10 = make_float4(0, 0, 0, 0), s11 = make_float4(0, 0, 0, 0);
#pragma unroll 8
  for (int m = 0; m < 32; ++m) {
    float l0 = sL[n0c * 32 + m];
    float l1 = sL[(n0c + 1) * 32 + m];
    float4 v0 = *(const float4*)&src[m * C2 + c0];
    float4 v1 = *(const float4*)&src[m * C2 + c0 + 4];
    FMA4(s00, l0, v0);
    FMA4(s01, l0, v1);
    FMA4(s10, l1, v0);
    FMA4(s11, l1, v1);
  }
  if (REC) {
    float4 a = *(const float4*)&dst[n0c * C2 + c0];
    float4 bq = *(const float4*)&dst[n0c * C2 + c0 + 4];
    float4 c = *(const float4*)&dst[(n0c + 1) * C2 + c0];
    float4 d = *(const float4*)&dst[(n0c + 1) * C2 + c0 + 4];
    s00.x = 2.0f * s00.x - a.x;  s00.y = 2.0f * s00.y - a.y;
    s00.z = 2.0f * s00.z - a.z;  s00.w = 2.0f * s00.w - a.w;
    s01.x = 2.0f * s01.x - bq.x; s01.y = 2.0f * s01.y - bq.y;
    s01.z = 2.0f * s01.z - bq.z; s01.w = 2.0f * s01.w - bq.w;
    s10.x = 2.0f * s10.x - c.x;  s10.y = 2.0f * s10.y - c.y;
    s10.z = 2.0f * s10.z - c.z;  s10.w = 2.0f * s10.w - c.w;
    s11.x = 2.0f * s11.x - d.x;  s11.y = 2.0f * s11.y - d.y;
    s11.z = 2.0f * s11.z - d.z;  s11.w = 2.0f * s11.w - d.w;
  }
  *(float4*)&dst[n0c * C2 + c0] = s00;
  *(float4*)&dst[n0c * C2 + c0 + 4] = s01;
  *(float4*)&dst[(n0c + 1) * C2 + c0] = s10;
  *(float4*)&dst[(n0c + 1) * C2 + c0 + 4] = s11;
}

__global__ __launch_bounds__(256, 3) void dgcnn_kernel(
    const float* __restrict__ x,
    const float* __restrict__ ws,
    const float* __restrict__ fc_w,
    const float* __restrict__ fc_b,
    float* __restrict__ out) {
  __shared__ __align__(16) float sL[1024];
  __shared__ __align__(16) float A1[NB * C1];
  __shared__ __align__(16) float B1[NB * C1];
  __shared__ __align__(16) float A2[NB * C2];
  __shared__ __align__(16) float B2[NB * C2];
  __shared__ float red[8];

  const int tid = threadIdx.x;
  const int b = blockIdx.x;
  const float* bias1 = ws + WS_BIAS1;
  const float* bias2 = ws + WS_BIAS2;
  const float* W1p = ws + WS_W1P;
  const float* W2p = ws + WS_W2P;

  for (int i = tid; i < 1024; i += 256) sL[i] = ws[WS_LAP + i];
  const float* xb = x + (size_t)b * (NB * C1);
  for (int i = tid; i < NB * C1; i += 256) A1[i] = xb[i];
  __syncthreads();

  const int o0 = (tid & 31) * 4;
  const int n0 = (tid >> 5) * 4;
  float acc[4][4];
#pragma unroll
  for (int i = 0; i < 4; ++i)
#pragma unroll
    for (int j = 0; j < 4; ++j) acc[i][j] = 0.0f;

  // ---------- layer 1 ----------
  einsum_acc<C1>(A1, W1p + 0 * C1 * HDIM, n0, o0, acc);   // k=1 term: x
  cheb60<false>(B1, A1, sL, tid);                         // B1 = L @ x
  __syncthreads();
  einsum_acc<C1>(B1, W1p + 1 * C1 * HDIM, n0, o0, acc);   // k=2: T1
  cheb60<true>(A1, B1, sL, tid);                          // A1 = 2 L T1 - x
  __syncthreads();
  einsum_acc<C1>(A1, W1p + 2 * C1 * HDIM, n0, o0, acc);   // k=3: T2
  cheb60<true>(B1, A1, sL, tid);                          // B1 = 2 L T2 - T1
  __syncthreads();
  einsum_acc<C1>(B1, W1p + 3 * C1 * HDIM, n0, o0, acc);   // k=4: T3

  // h = relu(acc + bias1') -> A2
  {
    float4 bv = *(const float4*)&bias1[o0];
#pragma unroll
    for (int i = 0; i < 4; ++i) {
      float4 hv;
      hv.x = fmaxf(acc[i][0] + bv.x, 0.0f);
      hv.y = fmaxf(acc[i][1] + bv.y, 0.0f);
      hv.z = fmaxf(acc[i][2] + bv.z, 0.0f);
      hv.w = fmaxf(acc[i][3] + bv.w, 0.0f);
      *(float4*)&A2[(n0 + i) * C2 + o0] = hv;
    }
  }
  __syncthreads();

  // ---------- layer 2 ----------
#pragma unroll
  for (int i = 0; i < 4; ++i)
#pragma unroll
    for (int j = 0; j < 4; ++j) acc[i][j] = 0.0f;

  einsum_acc<C2>(A2, W2p + 0 * C2 * HDIM, n0, o0, acc);   // k=1: h
  cheb128<false>(B2, A2, sL, tid);                        // B2 = L h
  __syncthreads();
  einsum_acc<C2>(B2, W2p + 1 * C2 * HDIM, n0, o0, acc);   // k=2
  cheb128<true>(A2, B2, sL, tid);                         // A2 = 2 L T1 - h
  __syncthreads();
  einsum_acc<C2>(A2, W2p + 2 * C2 * HDIM, n0, o0, acc);   // k=3
  cheb128<true>(B2, A2, sL, tid);                         // B2 = 2 L T2 - T1
  __syncthreads();
  einsum_acc<C2>(B2, W2p + 3 * C2 * HDIM, n0, o0, acc);   // k=4

  // h2 = relu(acc + bias2') -> A2 (nobody reads A2 in this phase)
  {
    float4 bv = *(const float4*)&bias2[o0];
#pragma unroll
    for (int i = 0; i < 4; ++i) {
      float4 hv;
      hv.x = fmaxf(acc[i][0] + bv.x, 0.0f);
      hv.y = fmaxf(acc[i][1] + bv.y, 0.0f);
      hv.z = fmaxf(acc[i][2] + bv.z, 0.0f);
      hv.w = fmaxf(acc[i][3] + bv.w, 0.0f);
      *(float4*)&A2[(n0 + i) * C2 + o0] = hv;
    }
  }
  __syncthreads();

  // ---------- fc: out[b][j] = sum_i h2_flat[i] * fc_w[j][i] + fc_b[j] ----------
  float p0 = 0.0f, p1 = 0.0f;
#pragma unroll
  for (int r = 0; r < 16; ++r) {
    int idx = r * 256 + tid;
    float v = A2[idx];
    p0 = fmaf(v, fc_w[idx], p0);
    p1 = fmaf(v, fc_w[4096 + idx], p1);
  }
#pragma unroll
  for (int off = 32; off >= 1; off >>= 1) {
    p0 += __shfl_xor(p0, off);
    p1 += __shfl_xor(p1, off);
  }
  if ((tid & 63) == 0) {
    red[(tid >> 6) * 2 + 0] = p0;
    red[(tid >> 6) * 2 + 1] = p1;
  }
  __syncthreads();
  if (tid < 2) {
    float s = red[tid] + red[2 + tid] + red[4 + tid] + red[6 + tid] + fc_b[tid];
    out[b * 2 + tid] = s;
  }
}

extern "C" void kernel_launch(void* const* d_in, const int* in_sizes, int n_in,
                              void* d_out, int out_size, void* d_ws, size_t ws_size,
                              hipStream_t stream) {
  const float* x        = (const float*)d_in[0];
  const float* adj      = (const float*)d_in[1];
  const float* adj_bias = (const float*)d_in[2];
  const float* w1       = (const float*)d_in[3];
  const float* b1       = (const float*)d_in[4];
  const float* w2       = (const float*)d_in[5];
  const float* b2       = (const float*)d_in[6];
  const float* fc_w     = (const float*)d_in[7];
  const float* fc_b     = (const float*)d_in[8];
  float* out = (float*)d_out;
  float* ws  = (float*)d_ws;

  prep_kernel<<<33, 256, 0, stream>>>(adj, adj_bias, w1, b1, w2, b2, ws);
  dgcnn_kernel<<<8192, 256, 0, stream>>>(x, ws, fc_w, fc_b, out);
}

// Round 3
// 215.825 us; speedup vs baseline: 5.1548x; 5.1548x over previous
//
#include <hip/hip_runtime.h>

typedef unsigned short u16;
typedef short bf16x8 __attribute__((ext_vector_type(8)));
typedef short short4v __attribute__((ext_vector_type(4)));
typedef float f32x4 __attribute__((ext_vector_type(4)));

#define MFMA16(a, b, c) __builtin_amdgcn_mfma_f32_16x16x32_bf16((a), (b), (c), 0, 0, 0)

__device__ __forceinline__ u16 f2bf(float f) {
  unsigned u = __builtin_bit_cast(unsigned, f);
  u += 0x7FFFu + ((u >> 16) & 1u);
  return (u16)(u >> 16);
}

// ws byte offsets
#define WS_MGF   0         // bf16 [8 jt][64 lane][8 j]   B-frags of M^T  (8192 B)
#define WS_WT1F  8192      // bf16 [8 ot][8 ks][64][8]    B-frags of Wp1  (65536 B)
#define WS_WT2F  73728     // bf16 [8 mt][16 ks][64][8]   A-frags of Wp2  (131072 B)
#define WS_B1    204800    // f32 [128]  bias1 + T0-fold
#define WS_B2    205312    // f32 [128]  bias2 + T0-fold

__global__ void prep_kernel(const float* __restrict__ adj,
                            const float* __restrict__ adj_bias,
                            const float* __restrict__ w1,
                            const float* __restrict__ b1,
                            const float* __restrict__ w2,
                            const float* __restrict__ b2,
                            char* __restrict__ ws) {
  const int tid = threadIdx.x;
  if (blockIdx.x == 0) {
    __shared__ float sa[1024], Ls[1024], L2s[1024], L3s[1024], sdre[32];
    float bias = adj_bias[0];
    for (int i = tid; i < 1024; i += 256) sa[i] = fmaxf(adj[i] + bias, 0.0f);
    __syncthreads();
    if (tid < 32) {
      float s = 0.0f;
      for (int c = 0; c < 32; ++c) s += sa[tid * 32 + c];
      sdre[tid] = 1.0f / sqrtf(s + 1e-5f);
    }
    __syncthreads();
    for (int i = tid; i < 1024; i += 256) {
      int n = i >> 5, c = i & 31;
      Ls[i] = (n == c ? 1.0f : 0.0f) - sdre[n] * sa[i] * sdre[c];
    }
    __syncthreads();
    for (int i = tid; i < 1024; i += 256) {
      int r = i >> 5, c = i & 31;
      float s = 0.0f;
      for (int m = 0; m < 32; ++m) s += Ls[r * 32 + m] * Ls[m * 32 + c];
      L2s[i] = s;
    }
    __syncthreads();
    for (int i = tid; i < 1024; i += 256) {
      int r = i >> 5, c = i & 31;
      float s = 0.0f;
      for (int m = 0; m < 32; ++m) s += L2s[r * 32 + m] * Ls[m * 32 + c];
      L3s[i] = s;
    }
    __syncthreads();
    // M stacked [128x32]: rows 0-31 I, 32-63 L, 64-95 2L^2-I, 96-127 4L^3-3L.
    // Stored as B-fragments of M^T: MGf[jt][lane][j] = M[col=jt*16+(lane&15)][k=(lane>>4)*8+j]
    u16* MGf = (u16*)(ws + WS_MGF);
    for (int i = tid; i < 4096; i += 256) {
      int jt = i >> 9, lane = (i >> 3) & 63, j = i & 7;
      int col = jt * 16 + (lane & 15);
      int k = ((lane >> 4) << 3) + j;
      int kk = col >> 5, np = col & 31;
      float v;
      if (kk == 0)      v = (np == k) ? 1.0f : 0.0f;
      else if (kk == 1) v = Ls[np * 32 + k];
      else if (kk == 2) v = 2.0f * L2s[np * 32 + k] - (np == k ? 1.0f : 0.0f);
      else              v = 4.0f * L3s[np * 32 + k] - 3.0f * Ls[np * 32 + k];
      MGf[i] = f2bf(v);
    }
    // biases with T0(=ones) term folded in
    float* B1 = (float*)(ws + WS_B1);
    float* B2 = (float*)(ws + WS_B2);
    if (tid < 128) {
      float s = b1[tid];
      for (int c = 0; c < 60; ++c) s += w1[(c * 5) * 128 + tid];
      B1[tid] = s;
    } else {
      int o = tid - 128;
      float s = b2[o];
      for (int c = 0; c < 128; ++c) s += w2[(c * 5) * 128 + o];
      B2[o] = s;
    }
  } else {
    // frag-order packing of weights (k-term-major kc, c padded 60->64 for layer1)
    u16* WT1F = (u16*)(ws + WS_WT1F);
    u16* WT2F = (u16*)(ws + WS_WT2F);
    int g = (blockIdx.x - 1) * 256 + tid;
    for (int i = g; i < 32768; i += 16 * 256) {
      int ot = i >> 12, ks = (i >> 9) & 7, lane = (i >> 3) & 63, j = i & 7;
      int o = ot * 16 + (lane & 15);
      int kc = ks * 32 + ((lane >> 4) << 3) + j;
      int k = kc >> 6, c = kc & 63;
      WT1F[i] = (c < 60) ? f2bf(w1[(c * 5 + k + 1) * 128 + o]) : (u16)0;
    }
    for (int i = g; i < 65536; i += 16 * 256) {
      int mt = i >> 13, ks = (i >> 9) & 15, lane = (i >> 3) & 63, j = i & 7;
      int o = mt * 16 + (lane & 15);
      int kc = ks * 32 + ((lane >> 4) << 3) + j;
      int k = kc >> 7, c = kc & 127;
      WT2F[i] = f2bf(w2[(c * 5 + k + 1) * 128 + o]);
    }
  }
}

__global__ __launch_bounds__(256, 3) void dgcnn_kernel(
    const float* __restrict__ x,
    const char* __restrict__ ws,
    const float* __restrict__ fc_w,
    const float* __restrict__ fc_b,
    float* __restrict__ out) {
  // LDS arena (phase-aliased):
  //   Xt  [64][40] bf16 @0      (5120)   x^T, c rows zero-padded 60..63
  //   Ht  [128][40] bf16 @0     (10240)  layer1 out^T (over dead Xt)
  //   Y1  [32][264] bf16 @10752 (16896)  cheb terms layer1, A-operand layout
  //   Y2  [32][520] bf16 @10752 (33280)  cheb terms layer2 (over dead Y1)
  //   H2  [32][132] f32 @0      (16896)  layer2 out (over dead Ht+Y2-head, after sync)
  __shared__ __align__(16) char arena[44032];
  __shared__ float red[8];
  u16* Xt = (u16*)arena;
  u16* Ht = (u16*)arena;
  u16* Y1 = (u16*)(arena + 10752);
  u16* Y2 = (u16*)(arena + 10752);
  float* H2 = (float*)arena;

  const u16* MGf  = (const u16*)(ws + WS_MGF);
  const u16* WT1F = (const u16*)(ws + WS_WT1F);
  const u16* WT2F = (const u16*)(ws + WS_WT2F);
  const float* bias1 = (const float*)(ws + WS_B1);
  const float* bias2 = (const float*)(ws + WS_B2);

  const int tid = threadIdx.x;
  const int w = tid >> 6, lane = tid & 63;
  const int l15 = lane & 15, q = lane >> 4;
  const int b = blockIdx.x;
  const f32x4 z4 = {0.0f, 0.0f, 0.0f, 0.0f};

  for (int i = tid; i < 2560; i += 256) Xt[i] = 0;
  // M^T B-fragments for this wave's two 16-wide column tiles (reused L1-G1 & L2-G1)
  bf16x8 mB0 = *(const bf16x8*)(MGf + ((2 * w + 0) * 64 + lane) * 8);
  bf16x8 mB1 = *(const bf16x8*)(MGf + ((2 * w + 1) * 64 + lane) * 8);
  __syncthreads();
  const float* xb = x + (size_t)b * 1920;
  for (int i = tid; i < 1920; i += 256) {
    int n = i / 60, c = i - n * 60;
    Xt[c * 40 + n] = f2bf(xb[i]);
  }
  __syncthreads();

  // ---- L1-G1: Y1^T = X^T @ M^T  (D rows = c contiguous) ----
  {
    f32x4 acc[4][2];
#pragma unroll
    for (int mt = 0; mt < 4; ++mt) {
      bf16x8 aX = *(const bf16x8*)&Xt[(mt * 16 + l15) * 40 + q * 8];
      acc[mt][0] = MFMA16(aX, mB0, z4);
      acc[mt][1] = MFMA16(aX, mB1, z4);
    }
#pragma unroll
    for (int mt = 0; mt < 4; ++mt)
#pragma unroll
      for (int jt = 0; jt < 2; ++jt) {
        int np = jt * 16 + l15;       // col -> (k=w, n')
        int cb = mt * 16 + q * 4;     // row base (c)
        short4v v;
        v[0] = (short)f2bf(acc[mt][jt][0]);
        v[1] = (short)f2bf(acc[mt][jt][1]);
        v[2] = (short)f2bf(acc[mt][jt][2]);
        v[3] = (short)f2bf(acc[mt][jt][3]);
        *(short4v*)&Y1[np * 264 + w * 64 + cb] = v;
      }
  }
  __syncthreads();

  // ---- einsum1: H[n][o] = Y1[n][kc] @ Wp1[kc][o], relu+bias -> Ht[o][n] ----
  {
    f32x4 acc[2][2] = {{z4, z4}, {z4, z4}};
#pragma unroll
    for (int ks = 0; ks < 8; ++ks) {
      bf16x8 a0 = *(const bf16x8*)&Y1[(l15) * 264 + ks * 32 + q * 8];
      bf16x8 a1 = *(const bf16x8*)&Y1[(16 + l15) * 264 + ks * 32 + q * 8];
      bf16x8 b0 = *(const bf16x8*)(WT1F + (((2 * w + 0) * 8 + ks) * 64 + lane) * 8);
      bf16x8 b1 = *(const bf16x8*)(WT1F + (((2 * w + 1) * 8 + ks) * 64 + lane) * 8);
      acc[0][0] = MFMA16(a0, b0, acc[0][0]);
      acc[0][1] = MFMA16(a0, b1, acc[0][1]);
      acc[1][0] = MFMA16(a1, b0, acc[1][0]);
      acc[1][1] = MFMA16(a1, b1, acc[1][1]);
    }
#pragma unroll
    for (int ot = 0; ot < 2; ++ot) {
      int o = (2 * w + ot) * 16 + l15;
      float bv = bias1[o];
#pragma unroll
      for (int mt = 0; mt < 2; ++mt) {
        int nb = mt * 16 + q * 4;
        short4v v;
        v[0] = (short)f2bf(fmaxf(acc[mt][ot][0] + bv, 0.0f));
        v[1] = (short)f2bf(fmaxf(acc[mt][ot][1] + bv, 0.0f));
        v[2] = (short)f2bf(fmaxf(acc[mt][ot][2] + bv, 0.0f));
        v[3] = (short)f2bf(fmaxf(acc[mt][ot][3] + bv, 0.0f));
        *(short4v*)&Ht[o * 40 + nb] = v;
      }
    }
  }
  __syncthreads();

  // ---- L2-G1: Y2^T = H^T @ M^T ----
  {
    f32x4 acc[8][2];
#pragma unroll
    for (int mt = 0; mt < 8; ++mt) {
      bf16x8 aH = *(const bf16x8*)&Ht[(mt * 16 + l15) * 40 + q * 8];
      acc[mt][0] = MFMA16(aH, mB0, z4);
      acc[mt][1] = MFMA16(aH, mB1, z4);
    }
#pragma unroll
    for (int mt = 0; mt < 8; ++mt)
#pragma unroll
      for (int jt = 0; jt < 2; ++jt) {
        int np = jt * 16 + l15;
        int ob = mt * 16 + q * 4;
        short4v v;
        v[0] = (short)f2bf(acc[mt][jt][0]);
        v[1] = (short)f2bf(acc[mt][jt][1]);
        v[2] = (short)f2bf(acc[mt][jt][2]);
        v[3] = (short)f2bf(acc[mt][jt][3]);
        *(short4v*)&Y2[np * 520 + w * 128 + ob] = v;
      }
  }
  __syncthreads();

  // ---- einsum2 (flipped): D[o][n] = Wp2^T[o][kc] @ Y2^T[kc][n] -> H2[n][o] float4 ----
  {
    f32x4 acc[2][2] = {{z4, z4}, {z4, z4}};  // [ot][nt]
#pragma unroll
    for (int ks = 0; ks < 16; ++ks) {
      bf16x8 aw0 = *(const bf16x8*)(WT2F + (((2 * w + 0) * 16 + ks) * 64 + lane) * 8);
      bf16x8 aw1 = *(const bf16x8*)(WT2F + (((2 * w + 1) * 16 + ks) * 64 + lane) * 8);
      bf16x8 by0 = *(const bf16x8*)&Y2[(l15) * 520 + ks * 32 + q * 8];
      bf16x8 by1 = *(const bf16x8*)&Y2[(16 + l15) * 520 + ks * 32 + q * 8];
      acc[0][0] = MFMA16(aw0, by0, acc[0][0]);
      acc[0][1] = MFMA16(aw0, by1, acc[0][1]);
      acc[1][0] = MFMA16(aw1, by0, acc[1][0]);
      acc[1][1] = MFMA16(aw1, by1, acc[1][1]);
    }
    __syncthreads();  // all Y2 reads done before H2 (overlapping region) is written
#pragma unroll
    for (int ot = 0; ot < 2; ++ot) {
      int ob = (2 * w + ot) * 16 + q * 4;  // row base (o), contiguous 4 per lane
      float4 bv = *(const float4*)&bias2[ob];
#pragma unroll
      for (int nt = 0; nt < 2; ++nt) {
        int n = nt * 16 + l15;
        float4 hv;
        hv.x = fmaxf(acc[ot][nt][0] + bv.x, 0.0f);
        hv.y = fmaxf(acc[ot][nt][1] + bv.y, 0.0f);
        hv.z = fmaxf(acc[ot][nt][2] + bv.z, 0.0f);
        hv.w = fmaxf(acc[ot][nt][3] + bv.w, 0.0f);
        *(float4*)&H2[n * 132 + ob] = hv;
      }
    }
  }
  __syncthreads();

  // ---- fc: out[b][j] = sum_i h2_flat[i] * fc_w[j][i] + fc_b[j] ----
  float p0 = 0.0f, p1 = 0.0f;
#pragma unroll
  for (int r = 0; r < 16; ++r) {
    int idx = r * 256 + tid;
    float v = H2[(idx >> 7) * 132 + (idx & 127)];
    p0 = fmaf(v, fc_w[idx], p0);
    p1 = fmaf(v, fc_w[4096 + idx], p1);
  }
#pragma unroll
  for (int off = 32; off >= 1; off >>= 1) {
    p0 += __shfl_xor(p0, off);
    p1 += __shfl_xor(p1, off);
  }
  if ((tid & 63) == 0) {
    red[(tid >> 6) * 2 + 0] = p0;
    red[(tid >> 6) * 2 + 1] = p1;
  }
  __syncthreads();
  if (tid < 2) {
    out[b * 2 + tid] = red[tid] + red[2 + tid] + red[4 + tid] + red[6 + tid] + fc_b[tid];
  }
}

extern "C" void kernel_launch(void* const* d_in, const int* in_sizes, int n_in,
                              void* d_out, int out_size, void* d_ws, size_t ws_size,
                              hipStream_t stream) {
  const float* x        = (const float*)d_in[0];
  const float* adj      = (const float*)d_in[1];
  const float* adj_bias = (const float*)d_in[2];
  const float* w1       = (const float*)d_in[3];
  const float* b1       = (const float*)d_in[4];
  const float* w2       = (const float*)d_in[5];
  const float* b2       = (const float*)d_in[6];
  const float* fc_w     = (const float*)d_in[7];
  const float* fc_b     = (const float*)d_in[8];
  float* out = (float*)d_out;
  char* ws   = (char*)d_ws;

  prep_kernel<<<17, 256, 0, stream>>>(adj, adj_bias, w1, b1, w2, b2, ws);
  dgcnn_kernel<<<8192, 256, 0, stream>>>(x, ws, fc_w, fc_b, out);
}

// Round 4
// 206.380 us; speedup vs baseline: 5.3907x; 1.0458x over previous
//
#include <hip/hip_runtime.h>

typedef unsigned short u16;
typedef unsigned int u32;
typedef short bf16x8 __attribute__((ext_vector_type(8)));
typedef float f32x4 __attribute__((ext_vector_type(4)));

#define MFMA16(a, b, c) __builtin_amdgcn_mfma_f32_16x16x32_bf16((a), (b), (c), 0, 0, 0)

__device__ __forceinline__ u16 f2bf(float f) {
  u32 u = __builtin_bit_cast(u32, f);
  u += 0x7FFFu + ((u >> 16) & 1u);
  return (u16)(u >> 16);
}
// packed f32x2 -> bf16x2 (round-nearest-even); HW inst on gfx950
__device__ __forceinline__ u32 pk2bf(float a, float b) {
#if __has_builtin(__builtin_amdgcn_cvt_pk_bf16_f32)
  auto v = __builtin_amdgcn_cvt_pk_bf16_f32(a, b);
  return __builtin_bit_cast(u32, v);
#else
  return (u32)f2bf(a) | ((u32)f2bf(b) << 16);
#endif
}

// ws byte offsets
#define WS_MGF   0         // bf16 [8 jt][64 lane][8 j]        B-frags of M^T   (8192 B)
#define WS_WT1F  8192      // bf16 [8 ot][8 ks][64][8]         B-frags of Wp1   (65536 B)
#define WS_WT2F  73728     // bf16 [8 mt][2 h][8 ks][64][8]    A-frags of Wp2^T (131072 B)
#define WS_B1    204800    // f32 [128]  bias1 + T0-fold
#define WS_B2    205312    // f32 [128]  bias2 + T0-fold

__global__ void prep_kernel(const float* __restrict__ adj,
                            const float* __restrict__ adj_bias,
                            const float* __restrict__ w1,
                            const float* __restrict__ b1,
                            const float* __restrict__ w2,
                            const float* __restrict__ b2,
                            char* __restrict__ ws) {
  const int tid = threadIdx.x;
  if (blockIdx.x == 0) {
    __shared__ float sa[1024], Ls[1024], L2s[1024], L3s[1024], sdre[32];
    float bias = adj_bias[0];
    for (int i = tid; i < 1024; i += 256) sa[i] = fmaxf(adj[i] + bias, 0.0f);
    __syncthreads();
    if (tid < 32) {
      float s = 0.0f;
      for (int c = 0; c < 32; ++c) s += sa[tid * 32 + c];
      sdre[tid] = 1.0f / sqrtf(s + 1e-5f);
    }
    __syncthreads();
    for (int i = tid; i < 1024; i += 256) {
      int n = i >> 5, c = i & 31;
      Ls[i] = (n == c ? 1.0f : 0.0f) - sdre[n] * sa[i] * sdre[c];
    }
    __syncthreads();
    for (int i = tid; i < 1024; i += 256) {
      int r = i >> 5, c = i & 31;
      float s = 0.0f;
      for (int m = 0; m < 32; ++m) s += Ls[r * 32 + m] * Ls[m * 32 + c];
      L2s[i] = s;
    }
    __syncthreads();
    for (int i = tid; i < 1024; i += 256) {
      int r = i >> 5, c = i & 31;
      float s = 0.0f;
      for (int m = 0; m < 32; ++m) s += L2s[r * 32 + m] * Ls[m * 32 + c];
      L3s[i] = s;
    }
    __syncthreads();
    // M stacked [128x32]: rows 0-31 I, 32-63 L, 64-95 2L^2-I, 96-127 4L^3-3L.
    // B-fragments of M^T: MGf[jt][lane][j] = M[col=jt*16+(lane&15)][k=(lane>>4)*8+j]
    u16* MGf = (u16*)(ws + WS_MGF);
    for (int i = tid; i < 4096; i += 256) {
      int jt = i >> 9, lane = (i >> 3) & 63, j = i & 7;
      int col = jt * 16 + (lane & 15);
      int k = ((lane >> 4) << 3) + j;
      int kk = col >> 5, np = col & 31;
      float v;
      if (kk == 0)      v = (np == k) ? 1.0f : 0.0f;
      else if (kk == 1) v = Ls[np * 32 + k];
      else if (kk == 2) v = 2.0f * L2s[np * 32 + k] - (np == k ? 1.0f : 0.0f);
      else              v = 4.0f * L3s[np * 32 + k] - 3.0f * Ls[np * 32 + k];
      MGf[i] = f2bf(v);
    }
    // biases with T0(=ones) term folded in
    float* B1 = (float*)(ws + WS_B1);
    float* B2 = (float*)(ws + WS_B2);
    if (tid < 128) {
      float s = b1[tid];
      for (int c = 0; c < 60; ++c) s += w1[(c * 5) * 128 + tid];
      B1[tid] = s;
    } else {
      int o = tid - 128;
      float s = b2[o];
      for (int c = 0; c < 128; ++c) s += w2[(c * 5) * 128 + o];
      B2[o] = s;
    }
  } else {
    u16* WT1F = (u16*)(ws + WS_WT1F);
    u16* WT2F = (u16*)(ws + WS_WT2F);
    int g = (blockIdx.x - 1) * 256 + tid;
    // WT1F: kc = k*64 + c (c padded 60->64)
    for (int i = g; i < 32768; i += 16 * 256) {
      int ot = i >> 12, ks = (i >> 9) & 7, lane = (i >> 3) & 63, j = i & 7;
      int o = ot * 16 + (lane & 15);
      int kc = ks * 32 + ((lane >> 4) << 3) + j;
      int k = kc >> 6, c = kc & 63;
      WT1F[i] = (c < 60) ? f2bf(w1[(c * 5 + k + 1) * 128 + o]) : (u16)0;
    }
    // WT2F: A-frags of Wp2^T in half-interleaved kc order:
    // kc = (ks>>1)*128 + (ks&1)*32 + h*64 + q*8 + j, with kc = k*128 + c
    for (int i = g; i < 65536; i += 16 * 256) {
      int mt = i >> 13, h = (i >> 12) & 1, ks = (i >> 9) & 7;
      int lane = (i >> 3) & 63, j = i & 7;
      int kc = ((ks >> 1) << 7) + ((ks & 1) << 5) + (h << 6) + (((lane >> 4)) << 3) + j;
      int k = kc >> 7, c = kc & 127;
      int o = (mt << 4) + (lane & 15);
      WT2F[i] = f2bf(w2[(c * 5 + k + 1) * 128 + o]);
    }
  }
}

__global__ __launch_bounds__(256, 5) void dgcnn_kernel(
    const float* __restrict__ x,
    const char* __restrict__ ws,
    const float* __restrict__ fc_w,
    const float* __restrict__ fc_b,
    float* __restrict__ out) {
  // LDS arena (phase-aliased), 26.5 KB -> 5 blocks/CU:
  //   Xt [64][40]  bf16 @0      (5120)   x^T, rows 60..63 zeroed
  //   Ht [128][40] bf16 @0      (10240)  layer1 out^T (over dead Xt)
  //   Y  [32][264] bf16 @10240  (16896)  cheb terms: Y1 full (layer1) / Y2 halves (layer2)
  __shared__ __align__(16) char arena[27136];
  __shared__ float red[8];
  u16* Xt = (u16*)arena;
  u16* Ht = (u16*)arena;
  u16* Y  = (u16*)(arena + 10240);

  const u16* MGf  = (const u16*)(ws + WS_MGF);
  const u16* WT1F = (const u16*)(ws + WS_WT1F);
  const u16* WT2F = (const u16*)(ws + WS_WT2F);
  const float* bias1 = (const float*)(ws + WS_B1);
  const float* bias2 = (const float*)(ws + WS_B2);

  const int tid = threadIdx.x;
  const int w = tid >> 6, lane = tid & 63;
  const int l15 = lane & 15, q = lane >> 4;
  const int b = blockIdx.x;
  const f32x4 z4 = {0.0f, 0.0f, 0.0f, 0.0f};

  // zero pad rows 60..63 of Xt (disjoint from x-fill below -> one barrier)
  for (int i = tid; i < 160; i += 256) Xt[(60 + (i / 40)) * 40 + (i % 40)] = 0;
  // M^T B-fragments for this wave's two 16-col tiles (reused in L1-G1 and L2-G1)
  bf16x8 mB0 = *(const bf16x8*)(MGf + ((2 * w + 0) * 64 + lane) * 8);
  bf16x8 mB1 = *(const bf16x8*)(MGf + ((2 * w + 1) * 64 + lane) * 8);
  const float* xb = x + (size_t)b * 1920;
  for (int i = tid; i < 1920; i += 256) {
    int n = i / 60, c = i - n * 60;
    Xt[c * 40 + n] = f2bf(xb[i]);
  }
  __syncthreads();

  // ---- L1-G1: Y1^T = X^T @ M^T ----
  {
    f32x4 acc[4][2];
#pragma unroll
    for (int mt = 0; mt < 4; ++mt) {
      bf16x8 aX = *(const bf16x8*)&Xt[(mt * 16 + l15) * 40 + q * 8];
      acc[mt][0] = MFMA16(aX, mB0, z4);
      acc[mt][1] = MFMA16(aX, mB1, z4);
    }
    __syncthreads();  // Xt reads done; (also covers nothing else: Y writes below race-free)
#pragma unroll
    for (int mt = 0; mt < 4; ++mt)
#pragma unroll
      for (int jt = 0; jt < 2; ++jt) {
        int np = jt * 16 + l15;
        uint2 vv;
        vv.x = pk2bf(acc[mt][jt][0], acc[mt][jt][1]);
        vv.y = pk2bf(acc[mt][jt][2], acc[mt][jt][3]);
        *(uint2*)&Y[np * 264 + w * 64 + mt * 16 + q * 4] = vv;
      }
  }
  __syncthreads();

  // ---- einsum1: H[n][o] = Y1[n][kc] @ Wp1[kc][o], +bias relu -> Ht[o][n] ----
  {
    f32x4 acc[2][2] = {{z4, z4}, {z4, z4}};
#pragma unroll
    for (int ks = 0; ks < 8; ++ks) {
      bf16x8 a0 = *(const bf16x8*)&Y[(l15) * 264 + ks * 32 + q * 8];
      bf16x8 a1 = *(const bf16x8*)&Y[(16 + l15) * 264 + ks * 32 + q * 8];
      bf16x8 b0 = *(const bf16x8*)(WT1F + (((2 * w + 0) * 8 + ks) * 64 + lane) * 8);
      bf16x8 b1 = *(const bf16x8*)(WT1F + (((2 * w + 1) * 8 + ks) * 64 + lane) * 8);
      acc[0][0] = MFMA16(a0, b0, acc[0][0]);
      acc[0][1] = MFMA16(a0, b1, acc[0][1]);
      acc[1][0] = MFMA16(a1, b0, acc[1][0]);
      acc[1][1] = MFMA16(a1, b1, acc[1][1]);
    }
#pragma unroll
    for (int ot = 0; ot < 2; ++ot) {
      int o = (2 * w + ot) * 16 + l15;
      float bv = bias1[o];
#pragma unroll
      for (int mt = 0; mt < 2; ++mt) {
        uint2 vv;
        vv.x = pk2bf(fmaxf(acc[mt][ot][0] + bv, 0.0f), fmaxf(acc[mt][ot][1] + bv, 0.0f));
        vv.y = pk2bf(fmaxf(acc[mt][ot][2] + bv, 0.0f), fmaxf(acc[mt][ot][3] + bv, 0.0f));
        *(uint2*)&Ht[o * 40 + mt * 16 + q * 4] = vv;
      }
    }
  }
  __syncthreads();

  // ---- layer 2 in two o1-halves; einsum2 accumulates across halves in regs ----
  f32x4 acc2[2][2] = {{z4, z4}, {z4, z4}};  // [ot][nt]
#pragma unroll
  for (int h = 0; h < 2; ++h) {
    // L2-G1 half: Y2h^T = H^T(rows 64h..64h+63) @ M^T
    {
      f32x4 acc[4][2];
#pragma unroll
      for (int mtl = 0; mtl < 4; ++mtl) {
        int mt = 4 * h + mtl;
        bf16x8 aH = *(const bf16x8*)&Ht[(mt * 16 + l15) * 40 + q * 8];
        acc[mtl][0] = MFMA16(aH, mB0, z4);
        acc[mtl][1] = MFMA16(aH, mB1, z4);
      }
#pragma unroll
      for (int mtl = 0; mtl < 4; ++mtl)
#pragma unroll
        for (int jt = 0; jt < 2; ++jt) {
          int np = jt * 16 + l15;
          uint2 vv;
          vv.x = pk2bf(acc[mtl][jt][0], acc[mtl][jt][1]);
          vv.y = pk2bf(acc[mtl][jt][2], acc[mtl][jt][3]);
          *(uint2*)&Y[np * 264 + w * 64 + mtl * 16 + q * 4] = vv;
        }
    }
    __syncthreads();
    // einsum2 partial (flipped): D[o][n] += Wp2^T[o][kc in half] @ Y2h^T[kc][n]
#pragma unroll
    for (int ks = 0; ks < 8; ++ks) {
      bf16x8 aw0 = *(const bf16x8*)(WT2F + ((((2 * w + 0) * 2 + h) * 8 + ks) * 64 + lane) * 8);
      bf16x8 aw1 = *(const bf16x8*)(WT2F + ((((2 * w + 1) * 2 + h) * 8 + ks) * 64 + lane) * 8);
      bf16x8 by0 = *(const bf16x8*)&Y[(l15) * 264 + ks * 32 + q * 8];
      bf16x8 by1 = *(const bf16x8*)&Y[(16 + l15) * 264 + ks * 32 + q * 8];
      acc2[0][0] = MFMA16(aw0, by0, acc2[0][0]);
      acc2[0][1] = MFMA16(aw0, by1, acc2[0][1]);
      acc2[1][0] = MFMA16(aw1, by0, acc2[1][0]);
      acc2[1][1] = MFMA16(aw1, by1, acc2[1][1]);
    }
    __syncthreads();  // h=0: Y reads done before next half overwrites; h=1: before red[]
  }

  // ---- epilogue: bias2+relu in regs, fc directly from accumulators ----
  float p0 = 0.0f, p1 = 0.0f;
#pragma unroll
  for (int ot = 0; ot < 2; ++ot) {
    int ob = (2 * w + ot) * 16 + q * 4;  // o base, 4 contiguous per lane
    float4 bv = *(const float4*)&bias2[ob];
#pragma unroll
    for (int nt = 0; nt < 2; ++nt) {
      int n = nt * 16 + l15;
      float h0 = fmaxf(acc2[ot][nt][0] + bv.x, 0.0f);
      float h1 = fmaxf(acc2[ot][nt][1] + bv.y, 0.0f);
      float h2 = fmaxf(acc2[ot][nt][2] + bv.z, 0.0f);
      float h3 = fmaxf(acc2[ot][nt][3] + bv.w, 0.0f);
      float4 w0 = *(const float4*)&fc_w[n * 128 + ob];
      float4 w1v = *(const float4*)&fc_w[4096 + n * 128 + ob];
      p0 = fmaf(h0, w0.x, fmaf(h1, w0.y, fmaf(h2, w0.z, fmaf(h3, w0.w, p0))));
      p1 = fmaf(h0, w1v.x, fmaf(h1, w1v.y, fmaf(h2, w1v.z, fmaf(h3, w1v.w, p1))));
    }
  }
#pragma unroll
  for (int off = 32; off >= 1; off >>= 1) {
    p0 += __shfl_xor(p0, off);
    p1 += __shfl_xor(p1, off);
  }
  if (lane == 0) {
    red[w * 2 + 0] = p0;
    red[w * 2 + 1] = p1;
  }
  __syncthreads();
  if (tid < 2) {
    out[b * 2 + tid] = red[tid] + red[2 + tid] + red[4 + tid] + red[6 + tid] + fc_b[tid];
  }
}

extern "C" void kernel_launch(void* const* d_in, const int* in_sizes, int n_in,
                              void* d_out, int out_size, void* d_ws, size_t ws_size,
                              hipStream_t stream) {
  const float* x        = (const float*)d_in[0];
  const float* adj      = (const float*)d_in[1];
  const float* adj_bias = (const float*)d_in[2];
  const float* w1       = (const float*)d_in[3];
  const float* b1       = (const float*)d_in[4];
  const float* w2       = (const float*)d_in[5];
  const float* b2       = (const float*)d_in[6];
  const float* fc_w     = (const float*)d_in[7];
  const float* fc_b     = (const float*)d_in[8];
  float* out = (float*)d_out;
  char* ws   = (char*)d_ws;

  prep_kernel<<<17, 256, 0, stream>>>(adj, adj_bias, w1, b1, w2, b2, ws);
  dgcnn_kernel<<<8192, 256, 0, stream>>>(x, ws, fc_w, fc_b, out);
}